// Round 14
// baseline (533.601 us; speedup 1.0000x reference)
//
#include <hip/hip_runtime.h>

#define TT   65536
#define HID  256
#define EMBD 16
#define TMPD 128   // hidden layer width (TMP) == K of second GEMM
#define ED   128   // EVENT_DIM
#define TAU  5e-4f
#define EPS  1e-3f
#define NEGINF (-3.402823466e38f)
#define TPB  32            // timesteps per block (repair sweep)
#define CAPW (1u << 20)    // worklist capacity (1M entries)
#define CMAX 24
#define XDP  257           // x LDS pitch in doubles

typedef __bf16  bf16x8 __attribute__((ext_vector_type(8)));
typedef float   f32x4  __attribute__((ext_vector_type(4)));
typedef short   s16x8  __attribute__((ext_vector_type(8)));
typedef double  f64x4  __attribute__((ext_vector_type(4)));

__device__ inline unsigned short f2bf(float f) {
    __bf16 b = (__bf16)f;
    return __builtin_bit_cast(unsigned short, b);
}
__device__ inline float bf2f(unsigned short u) {
    unsigned int x = ((unsigned int)u) << 16;
    return __builtin_bit_cast(float, x);
}
__device__ inline bf16x8 load_frag(const unsigned short* p) {
    uint4 r = *reinterpret_cast<const uint4*>(p);
    return __builtin_bit_cast(bf16x8, r);
}
// h = lrelu(p+e); split to bf16 hi/lo
__device__ inline void split8(const float4& p0, const float4& p1,
                              const float4& e0, const float4& e1,
                              bf16x8& hi, bf16x8& lo)
{
    const float f[8] = {p0.x + e0.x, p0.y + e0.y, p0.z + e0.z, p0.w + e0.w,
                        p1.x + e1.x, p1.y + e1.y, p1.z + e1.z, p1.w + e1.w};
    s16x8 hs, ls;
    #pragma unroll
    for (int q = 0; q < 8; ++q) {
        const float h = fmaxf(f[q], 0.01f * f[q]);
        const unsigned short hb = f2bf(h);
        hs[q] = (short)hb;
        ls[q] = (short)f2bf(h - bf2f(hb));
    }
    hi = __builtin_bit_cast(bf16x8, hs);
    lo = __builtin_bit_cast(bf16x8, ls);
}

// ---------------------------------------------------------------------------
// W1 -> double (one-time; L2-resident 256 KB).
// ---------------------------------------------------------------------------
__global__ void __launch_bounds__(256) w1d_kernel(const float* __restrict__ W1,
                                                  double* __restrict__ W1d)
{
    const int e = blockIdx.x * 256 + threadIdx.x;
    W1d[e] = (double)W1[e];
}

// ---------------------------------------------------------------------------
// Probe: discover v_mfma_f64_16x16x4 operand packing on-device.
// Tests 8 combos: A m-fast/k-fast x B n-fast/k-fast x D normal/swapped.
// Writes matching combo 0..7 (or 0xFF) to pflag[0].
// ---------------------------------------------------------------------------
__global__ void __launch_bounds__(64) probe_kernel(unsigned int* __restrict__ pflag)
{
    const int l = threadIdx.x;
    const double a = (double)(l + 1);
    const double b = (double)(l * l + 3 * l + 7);
    f64x4 d = {0.0, 0.0, 0.0, 0.0};
    d = __builtin_amdgcn_mfma_f64_16x16x4f64(a, b, d, 0, 0, 0);

    int found = -1;
    #pragma unroll
    for (int c = 0; c < 8; ++c) {
        const int pA = c & 1, pB = (c >> 1) & 1, pD = (c >> 2) & 1;
        bool ok = true;
        #pragma unroll
        for (int r = 0; r < 4; ++r) {
            const int m = pD ? (l & 15) : (4 * (l >> 4) + r);
            const int n = pD ? (4 * (l >> 4) + r) : (l & 15);
            double exp = 0.0;
            #pragma unroll
            for (int k = 0; k < 4; ++k) {
                const int laneA = pA ? (m * 4 + k) : (m + 16 * k);
                const int laneB = pB ? (n * 4 + k) : (n + 16 * k);
                exp += (double)(laneA + 1) *
                       (double)(laneB * laneB + 3 * laneB + 7);
            }
            ok = ok && (d[r] == exp);
        }
        const unsigned long long bal = __ballot(ok);
        if (bal == 0xFFFFFFFFFFFFFFFFull && found < 0) found = c;
    }
    if (l == 0) pflag[0] = (found < 0) ? 0xFFu : (unsigned int)found;
}

// ---------------------------------------------------------------------------
// PRE via fp64 MFMA (runtime-selected packing). Early-out if probe failed.
// Block = 512 thr (8 waves, wave -> 16-col j tile), 16 t per block.
// ---------------------------------------------------------------------------
__global__ void __launch_bounds__(512) prem_kernel(
    const float* __restrict__ x, const double* __restrict__ W1d,
    const float* __restrict__ b1, float* __restrict__ pre,
    const unsigned int* __restrict__ pflag)
{
    const unsigned int c = pflag[0];
    if (c > 7u) return;
    const int pA = c & 1, pB = (c >> 1) & 1, pD = (c >> 2) & 1;

    const int tid = threadIdx.x;
    const int w   = tid >> 6;
    const int l   = tid & 63;
    const int t0  = blockIdx.x * 16;
    const int j0  = w * 16;

    __shared__ double xsd[16 * XDP];   // 32.9 KB

    for (int e = tid; e < 16 * HID; e += 512) {
        const int tt = e >> 8, k = e & 255;
        xsd[tt * XDP + k] = (double)x[(size_t)t0 * HID + e];
    }
    __syncthreads();

    const int mA = pA ? (l >> 2) : (l & 15);
    const int kA = pA ? (l & 3)  : (l >> 4);
    const int nB = pB ? (l >> 2) : (l & 15);
    const int kB = pB ? (l & 3)  : (l >> 4);

    const double* xrow = xsd + mA * XDP;
    const double* wcol = W1d + j0 + nB;

    f64x4 acc = {0.0, 0.0, 0.0, 0.0};
    #pragma unroll 4
    for (int k0 = 0; k0 < HID; k0 += 4) {
        const double a = xrow[k0 + kA];
        const double b = wcol[(size_t)(k0 + kB) * TMPD];
        acc = __builtin_amdgcn_mfma_f64_16x16x4f64(a, b, acc, 0, 0, 0);
    }
    #pragma unroll
    for (int r = 0; r < 4; ++r) {
        const int m = pD ? (l & 15) : (4 * (l >> 4) + r);
        const int n = pD ? (4 * (l >> 4) + r) : (l & 15);
        pre[(size_t)(t0 + m) * TMPD + j0 + n] =
            (float)(acc[r] + (double)b1[j0 + n]);
    }
}

// ---------------------------------------------------------------------------
// PRE fallback (fp64 VALU, double-staged x + W1d -> no per-k converts).
// Accumulation order identical to the known-good round-12 kernel.
// ---------------------------------------------------------------------------
__global__ void __launch_bounds__(128) prev_kernel(
    const float* __restrict__ x, const double* __restrict__ W1d,
    const float* __restrict__ b1, float* __restrict__ pre,
    const unsigned int* __restrict__ pflag)
{
    if (pflag[0] <= 7u) return;    // MFMA path handled it
    const int j  = threadIdx.x;
    const int t0 = blockIdx.x * 16;

    __shared__ double xsd[16 * XDP];
    for (int e = j; e < 16 * HID; e += 128)
        xsd[(e >> 8) * XDP + (e & 255)] = (double)x[(size_t)t0 * HID + e];
    __syncthreads();

    double acc[16];
    #pragma unroll
    for (int tt = 0; tt < 16; ++tt) acc[tt] = 0.0;

    #pragma unroll 2
    for (int k = 0; k < HID; ++k) {
        const double w = W1d[(size_t)k * TMPD + j];
        #pragma unroll
        for (int tt = 0; tt < 16; ++tt)
            acc[tt] += xsd[tt * XDP + k] * w;
    }
    const double bb = (double)b1[j];
    #pragma unroll
    for (int tt = 0; tt < 16; ++tt)
        pre[(size_t)(t0 + tt) * TMPD + j] = (float)(bb + acc[tt]);
}

// ---------------------------------------------------------------------------
// Simple PRE (small-ws fallback path only; round-12 known-good).
// ---------------------------------------------------------------------------
__global__ void __launch_bounds__(128) preold_kernel(const float* __restrict__ x,
                                                     const float* __restrict__ W1,
                                                     const float* __restrict__ b1,
                                                     float* __restrict__ pre)
{
    const int j  = threadIdx.x;
    const int t0 = blockIdx.x * 16;

    __shared__ float xs[16 * HID];
    for (int i = j; i < 16 * HID; i += 128)
        xs[i] = x[(size_t)t0 * HID + i];
    __syncthreads();

    double acc[16];
    #pragma unroll
    for (int tt = 0; tt < 16; ++tt) acc[tt] = 0.0;

    #pragma unroll 4
    for (int k = 0; k < HID; ++k) {
        const double w = (double)W1[k * TMPD + j];
        #pragma unroll
        for (int tt = 0; tt < 16; ++tt)
            acc[tt] += (double)xs[tt * HID + k] * w;
    }
    const double bb = (double)b1[j];
    #pragma unroll
    for (int tt = 0; tt < 16; ++tt)
        pre[(size_t)(t0 + tt) * TMPD + j] = (float)(bb + acc[tt]);
}

// ---------------------------------------------------------------------------
// W2 split (parallel): one (k,j) element per thread.
// ---------------------------------------------------------------------------
__global__ void __launch_bounds__(256) w2split_kernel(
    const float* __restrict__ W2,
    unsigned short* __restrict__ W2Th, unsigned short* __restrict__ W2Tl,
    float* __restrict__ W2Tf)
{
    const int gid = blockIdx.x * 256 + threadIdx.x;
    const int k = gid >> 7, j = gid & 127;
    const float v = W2[k * ED + j];
    const unsigned short hi = f2bf(v);
    const unsigned short lo = f2bf(v - bf2f(hi));
    W2Th[j * TMPD + k] = hi;
    W2Tl[j * TMPD + k] = lo;
    W2Tf[j * TMPD + k] = v;
}

// ---------------------------------------------------------------------------
// E2 (parallel, fp64 identical math) + E2T4 (k-quad packed) + zero meta.
// ---------------------------------------------------------------------------
__global__ void __launch_bounds__(128) e2z_kernel(
    const float* __restrict__ emb, const float* __restrict__ W1,
    float* __restrict__ E2, float* __restrict__ E2T4,
    unsigned int* __restrict__ meta)
{
    const int i = blockIdx.x;
    const int j = threadIdx.x;
    if (i == 0 && j < 8) meta[j] = 0;
    double a = 0.0;
    #pragma unroll
    for (int m = 0; m < EMBD; ++m)
        a += (double)emb[i * EMBD + m] * (double)W1[(HID + m) * TMPD + j];
    const float v = (float)a;
    E2[i * TMPD + j] = v;
    E2T4[(j >> 2) * 512 + i * 4 + (j & 3)] = v;
}

// ---------------------------------------------------------------------------
// Dp (parallel): block j, thread i, max-reduce over i.
// ---------------------------------------------------------------------------
__global__ void __launch_bounds__(128) dp_kernel(
    const float* __restrict__ E2, const float* __restrict__ W2Tf,
    float* __restrict__ Dp)
{
    const int j = blockIdx.x;
    const int i = threadIdx.x;
    __shared__ float red[2];

    const float* e2r = E2 + (size_t)i * TMPD;
    const float* w2r = W2Tf + (size_t)j * TMPD;
    float s = 0.f;
    #pragma unroll 4
    for (int k = 0; k < TMPD; ++k)
        s = fmaf(fabsf(e2r[k]), fabsf(w2r[k]), s);

    #pragma unroll
    for (int m = 1; m < 64; m <<= 1)
        s = fmaxf(s, __shfl_xor(s, m));
    if ((i & 63) == 0) red[i >> 6] = s;
    __syncthreads();
    if (i == 0) Dp[j] = fmaxf(red[0], red[1]) * 1.0001f + 1e-6f;
}

// ---------------------------------------------------------------------------
// L0 + classification. Block = 512 thr (8 waves), 128 t rows, all 128 j.
// ---------------------------------------------------------------------------
__global__ void __launch_bounds__(512, 1) l0_kernel(
    const float* __restrict__ pre,
    const unsigned short* __restrict__ W2Th, const unsigned short* __restrict__ W2Tl,
    const float* __restrict__ b2, const float* __restrict__ Dp,
    unsigned char* __restrict__ ftab,
    unsigned char* __restrict__ clist, unsigned char* __restrict__ ccnt,
    unsigned int* __restrict__ tlist, unsigned int* __restrict__ meta)
{
    const int tid = threadIdx.x;
    const int w   = tid >> 6;
    const int l   = tid & 63;
    const int ibase = (w >> 1) * 32;
    const int jhalf = w & 1;
    const int j0    = jhalf * 64;
    const int lc = l & 15, lg = l >> 4;
    const int t0 = blockIdx.x << 7;

    __shared__ float smA [2][128];
    __shared__ int   smAX[2][128];
    __shared__ float smW1[2][128];
    __shared__ int   smWX[2][128];
    __shared__ float smW2[2][128];
    __shared__ unsigned long long smMask[2][128];
    __shared__ float smThr[128];
    __shared__ int   smJ[128];

    // B fragments
    bf16x8 Bh[4][4], Bl[4][4];
    #pragma unroll
    for (int jt = 0; jt < 4; ++jt)
        #pragma unroll
        for (int kk = 0; kk < 4; ++kk) {
            const int row = j0 + jt * 16 + lc;
            const int kof = kk * 32 + (lg << 3);
            Bh[jt][kk] = load_frag(W2Th + row * TMPD + kof);
            Bl[jt][kk] = load_frag(W2Tl + row * TMPD + kof);
        }
    float b2v[4], dpv[4];
    #pragma unroll
    for (int jt = 0; jt < 4; ++jt) {
        b2v[jt] = b2[j0 + jt * 16 + lc];
        dpv[jt] = Dp[j0 + jt * 16 + lc];
    }

    // ---- MFMA: L0 = lrelu(PRE) @ W2 (split-bf16 3-pass) ----
    f32x4 acc[2][4];
    #pragma unroll
    for (int it = 0; it < 2; ++it)
        #pragma unroll
        for (int jt = 0; jt < 4; ++jt)
            acc[it][jt] = (f32x4){0.f, 0.f, 0.f, 0.f};

    const float4 z4 = {0.f, 0.f, 0.f, 0.f};
    #pragma unroll
    for (int kk = 0; kk < 4; ++kk) {
        const int kof = kk * 32 + (lg << 3);
        bf16x8 Ah[2], Al[2];
        #pragma unroll
        for (int it = 0; it < 2; ++it) {
            const float* pA = pre + (size_t)(t0 + ibase + it * 16 + lc) * TMPD + kof;
            const float4 p0 = *reinterpret_cast<const float4*>(pA);
            const float4 p1 = *reinterpret_cast<const float4*>(pA + 4);
            split8(p0, p1, z4, z4, Ah[it], Al[it]);
        }
        #pragma unroll
        for (int it = 0; it < 2; ++it)
            #pragma unroll
            for (int jt = 0; jt < 4; ++jt) {
                acc[it][jt] = __builtin_amdgcn_mfma_f32_16x16x32_bf16(Al[it], Bh[jt][kk], acc[it][jt], 0, 0, 0);
                acc[it][jt] = __builtin_amdgcn_mfma_f32_16x16x32_bf16(Ah[it], Bl[jt][kk], acc[it][jt], 0, 0, 0);
                acc[it][jt] = __builtin_amdgcn_mfma_f32_16x16x32_bf16(Ah[it], Bh[jt][kk], acc[it][jt], 0, 0, 0);
            }
    }

    // ---- pass 1: per-row A-top1/argmax and W-top2 within this half ----
    #pragma unroll
    for (int it = 0; it < 2; ++it) {
        #pragma unroll
        for (int r = 0; r < 4; ++r) {
            float av0 = acc[it][0][r] + b2v[0];
            float a1 = av0; int x1 = j0 + lc;
            float w1 = av0 + dpv[0]; int wx1 = j0 + lc; float w2 = NEGINF;
            #pragma unroll
            for (int jt = 1; jt < 4; ++jt) {
                const float av = acc[it][jt][r] + b2v[jt];
                const int   jj = j0 + jt * 16 + lc;
                if (av > a1) { a1 = av; x1 = jj; }
                const float wv = av + dpv[jt];
                if (wv > w1) { w2 = w1; w1 = wv; wx1 = jj; }
                else         { w2 = fmaxf(w2, wv); }
            }
            #pragma unroll
            for (int m = 1; m < 16; m <<= 1) {
                const float oa = __shfl_xor(a1, m);
                const int   ox = __shfl_xor(x1, m);
                if (oa > a1 || (oa == a1 && ox < x1)) { a1 = oa; x1 = ox; }
                const float ow1 = __shfl_xor(w1, m);
                const int   owx = __shfl_xor(wx1, m);
                const float ow2 = __shfl_xor(w2, m);
                const bool take = (ow1 > w1) || (ow1 == w1 && owx < wx1);
                const float loser = take ? w1 : ow1;
                w2 = fmaxf(w2, fmaxf(ow2, loser));
                if (take) { w1 = ow1; wx1 = owx; }
            }
            if (lc == 0) {
                const int row = ibase + it * 16 + 4 * lg + r;
                smA [jhalf][row] = a1;  smAX[jhalf][row] = x1;
                smW1[jhalf][row] = w1;  smWX[jhalf][row] = wx1;
                smW2[jhalf][row] = w2;
            }
        }
    }
    __syncthreads();

    // ---- merge 1: singleton test ----
    if (tid < 128) {
        const int row = tid, t = t0 + row;
        const float A0 = smA[0][row], A1 = smA[1][row];
        const int   X0 = smAX[0][row], X1 = smAX[1][row];
        const bool  h1 = (A1 > A0);
        const float astar = h1 ? A1 : A0;
        const int   jstar = h1 ? X1 : X0;
        const float c0 = (smWX[0][row] == jstar) ? smW2[0][row] : smW1[0][row];
        const float c1 = (smWX[1][row] == jstar) ? smW2[1][row] : smW1[1][row];
        const float M2 = fmaxf(c0, c1);
        const float thr = astar - Dp[jstar] - EPS;
        smJ[row] = jstar;
        if (thr > M2) {      // provably constant transition for all i
            smThr[row] = 3.0e38f;
            const unsigned int q = (unsigned int)jstar * 0x01010101u;
            const uint4 qv = make_uint4(q, q, q, q);
            uint4* dst = reinterpret_cast<uint4*>(ftab + (size_t)t * ED);
            #pragma unroll
            for (int u = 0; u < 8; ++u) dst[u] = qv;
        } else {
            smThr[row] = thr;
        }
    }
    __syncthreads();

    // ---- pass 2: candidate ballot (W_j >= thr) ----
    #pragma unroll
    for (int it = 0; it < 2; ++it) {
        #pragma unroll
        for (int r = 0; r < 4; ++r) {
            const int row = ibase + it * 16 + 4 * lg + r;
            const float thr = smThr[row];
            unsigned long long mask = 0ull;
            #pragma unroll
            for (int jt = 0; jt < 4; ++jt) {
                const float wv = acc[it][jt][r] + b2v[jt] + dpv[jt];
                const unsigned long long b = __ballot(wv >= thr);
                mask |= ((b >> (lg * 16)) & 0xFFFFull) << (jt * 16);
            }
            if (lc == 0) smMask[jhalf][row] = mask;
        }
    }
    __syncthreads();

    // ---- merge 2: extract candidates ----
    if (tid < 128) {
        const int row = tid, t = t0 + row;
        const float thr = smThr[row];
        if (thr < 1e38f) {
            unsigned long long m0 = smMask[0][row], m1 = smMask[1][row];
            const int cnt = __popcll(m0) + __popcll(m1);
            if (cnt > CMAX) {   // rare: flag whole t for full fp64 repair
                ccnt[t] = 0xFFu;
                const unsigned int q = ((unsigned int)smJ[row] | 0x80u) * 0x01010101u;
                const uint4 qv = make_uint4(q, q, q, q);
                uint4* dst = reinterpret_cast<uint4*>(ftab + (size_t)t * ED);
                #pragma unroll
                for (int u = 0; u < 8; ++u) dst[u] = qv;
            } else {
                int c = 0;
                while (m0) { const int b = __ffsll((unsigned long long)m0) - 1;
                             clist[(size_t)t * CMAX + c] = (unsigned char)b; ++c; m0 &= m0 - 1; }
                while (m1) { const int b = __ffsll((unsigned long long)m1) - 1;
                             clist[(size_t)t * CMAX + c] = (unsigned char)(64 + b); ++c; m1 &= m1 - 1; }
                ccnt[t] = (unsigned char)cnt;
                const unsigned int pos = atomicAdd(&meta[1], 1u);
                tlist[pos] = (unsigned int)t;
            }
        }
    }
}

// ---------------------------------------------------------------------------
// Tier-2 v5: E2T4 k-quad packed, float4 broadcast reads, cnt-adaptive width.
// ---------------------------------------------------------------------------
__global__ void __launch_bounds__(128) tier2_kernel(
    const float* __restrict__ pre, const float* __restrict__ E2T4,
    const float* __restrict__ W2Tf, const float* __restrict__ b2,
    const unsigned int* __restrict__ meta,
    const unsigned int* __restrict__ tlist, const unsigned char* __restrict__ ccnt,
    const unsigned char* __restrict__ clist, unsigned char* __restrict__ ftab)
{
    const int i = threadIdx.x;
    __shared__ float Ps[TMPD];
    __shared__ float Ws[8][TMPD];
    __shared__ float vb[8];
    __shared__ unsigned char clj[CMAX];
    __shared__ int scnt;

    const float4* e4p = reinterpret_cast<const float4*>(E2T4) + i;  // +kq*128

    const unsigned int n2 = meta[1];
    for (unsigned int u = blockIdx.x; u < n2; u += gridDim.x) {
        const int t = (int)tlist[u];
        if (i == 0) scnt = (int)ccnt[t];
        Ps[i] = pre[(size_t)t * TMPD + i];
        if (i < CMAX) clj[i] = clist[(size_t)t * CMAX + i];
        __syncthreads();                                   // A
        const int cnt = scnt;

        float t1 = NEGINF, t2 = NEGINF; int x1 = 0;
        for (int g0 = 0; g0 < cnt; g0 += 8) {
            const int gn = min(8, cnt - g0);
            for (int c = 0; c < gn; ++c)
                Ws[c][i] = W2Tf[(int)clj[g0 + c] * TMPD + i];
            if (i < 8) vb[i] = (i < gn) ? b2[clj[g0 + i]] : NEGINF;
            __syncthreads();                               // B

            float s[8] = {0.f, 0.f, 0.f, 0.f, 0.f, 0.f, 0.f, 0.f};
            if (gn <= 2) {
                #pragma unroll 4
                for (int kq = 0; kq < 32; ++kq) {
                    const float4 e4 = e4p[kq * ED];
                    const float4 p4 = *reinterpret_cast<const float4*>(&Ps[4 * kq]);
                    const float4 w0 = *reinterpret_cast<const float4*>(&Ws[0][4 * kq]);
                    const float4 w1 = *reinterpret_cast<const float4*>(&Ws[1][4 * kq]);
                    float h;
                    h = p4.x + e4.x; h = fmaxf(h, 0.01f * h);
                    s[0] = fmaf(h, w0.x, s[0]); s[1] = fmaf(h, w1.x, s[1]);
                    h = p4.y + e4.y; h = fmaxf(h, 0.01f * h);
                    s[0] = fmaf(h, w0.y, s[0]); s[1] = fmaf(h, w1.y, s[1]);
                    h = p4.z + e4.z; h = fmaxf(h, 0.01f * h);
                    s[0] = fmaf(h, w0.z, s[0]); s[1] = fmaf(h, w1.z, s[1]);
                    h = p4.w + e4.w; h = fmaxf(h, 0.01f * h);
                    s[0] = fmaf(h, w0.w, s[0]); s[1] = fmaf(h, w1.w, s[1]);
                }
            } else if (gn <= 4) {
                #pragma unroll 2
                for (int kq = 0; kq < 32; ++kq) {
                    const float4 e4 = e4p[kq * ED];
                    const float4 p4 = *reinterpret_cast<const float4*>(&Ps[4 * kq]);
                    const float4 w0 = *reinterpret_cast<const float4*>(&Ws[0][4 * kq]);
                    const float4 w1 = *reinterpret_cast<const float4*>(&Ws[1][4 * kq]);
                    const float4 w2 = *reinterpret_cast<const float4*>(&Ws[2][4 * kq]);
                    const float4 w3 = *reinterpret_cast<const float4*>(&Ws[3][4 * kq]);
                    float h;
                    h = p4.x + e4.x; h = fmaxf(h, 0.01f * h);
                    s[0] = fmaf(h, w0.x, s[0]); s[1] = fmaf(h, w1.x, s[1]);
                    s[2] = fmaf(h, w2.x, s[2]); s[3] = fmaf(h, w3.x, s[3]);
                    h = p4.y + e4.y; h = fmaxf(h, 0.01f * h);
                    s[0] = fmaf(h, w0.y, s[0]); s[1] = fmaf(h, w1.y, s[1]);
                    s[2] = fmaf(h, w2.y, s[2]); s[3] = fmaf(h, w3.y, s[3]);
                    h = p4.z + e4.z; h = fmaxf(h, 0.01f * h);
                    s[0] = fmaf(h, w0.z, s[0]); s[1] = fmaf(h, w1.z, s[1]);
                    s[2] = fmaf(h, w2.z, s[2]); s[3] = fmaf(h, w3.z, s[3]);
                    h = p4.w + e4.w; h = fmaxf(h, 0.01f * h);
                    s[0] = fmaf(h, w0.w, s[0]); s[1] = fmaf(h, w1.w, s[1]);
                    s[2] = fmaf(h, w2.w, s[2]); s[3] = fmaf(h, w3.w, s[3]);
                }
            } else {
                for (int kq = 0; kq < 32; ++kq) {
                    const float4 e4 = e4p[kq * ED];
                    const float4 p4 = *reinterpret_cast<const float4*>(&Ps[4 * kq]);
                    float4 wc[8];
                    #pragma unroll
                    for (int c = 0; c < 8; ++c)
                        wc[c] = *reinterpret_cast<const float4*>(&Ws[c][4 * kq]);
                    float h;
                    h = p4.x + e4.x; h = fmaxf(h, 0.01f * h);
                    #pragma unroll
                    for (int c = 0; c < 8; ++c) s[c] = fmaf(h, wc[c].x, s[c]);
                    h = p4.y + e4.y; h = fmaxf(h, 0.01f * h);
                    #pragma unroll
                    for (int c = 0; c < 8; ++c) s[c] = fmaf(h, wc[c].y, s[c]);
                    h = p4.z + e4.z; h = fmaxf(h, 0.01f * h);
                    #pragma unroll
                    for (int c = 0; c < 8; ++c) s[c] = fmaf(h, wc[c].z, s[c]);
                    h = p4.w + e4.w; h = fmaxf(h, 0.01f * h);
                    #pragma unroll
                    for (int c = 0; c < 8; ++c) s[c] = fmaf(h, wc[c].w, s[c]);
                }
            }

            for (int c = 0; c < gn; ++c) {
                const float v = s[c] + vb[c];
                const int jj = (int)clj[g0 + c];
                if (v > t1) { t2 = t1; t1 = v; x1 = jj; }
                else        { t2 = fmaxf(t2, v); }
            }
            __syncthreads();                               // C
        }
        unsigned char byte = (unsigned char)x1;
        if (t1 - t2 < TAU) byte |= 0x80u;
        ftab[(size_t)t * ED + i] = byte;
        __syncthreads();                                   // D
    }
}

// ---------------------------------------------------------------------------
// Compact flagged (t,i) byte-indices into a worklist.
// ---------------------------------------------------------------------------
__global__ void __launch_bounds__(256) compact_kernel(
    const unsigned char* __restrict__ ftab,
    unsigned int* __restrict__ meta, unsigned int* __restrict__ work)
{
    const unsigned int gid = blockIdx.x * 256 + threadIdx.x;
    const unsigned int v = reinterpret_cast<const unsigned int*>(ftab)[gid];
    const unsigned int flags = v & 0x80808080u;
    if (flags) {
        const int cnt = __popc(flags);
        unsigned int base = atomicAdd(meta, (unsigned int)cnt);
        #pragma unroll
        for (int b = 0; b < 4; ++b)
            if (v & (0x80u << (8 * b))) {
                if (base < CAPW) work[base] = gid * 4 + b;
                ++base;
            }
    }
}

// ---------------------------------------------------------------------------
// Candidate repair: one wave per flagged (t,i); fp64 logits only for j in C.
// ---------------------------------------------------------------------------
__global__ void __launch_bounds__(64) repair3_kernel(
    const float* __restrict__ pre, const float* __restrict__ E2,
    const float* __restrict__ W2Tf, const float* __restrict__ b2,
    const unsigned char* __restrict__ clist, const unsigned char* __restrict__ ccnt,
    const unsigned int* __restrict__ meta, const unsigned int* __restrict__ work,
    unsigned char* __restrict__ ftab)
{
    const int l = threadIdx.x;   // 0..63
    unsigned int n = meta[0];
    if (n > CAPW) n = CAPW;

    for (unsigned int u = blockIdx.x; u < n; u += gridDim.x) {
        const unsigned int e = work[u];
        const int t = (int)(e >> 7), i = (int)(e & 127u);

        float h0 = pre[(size_t)t * TMPD + l]      + E2[i * TMPD + l];
        float h1 = pre[(size_t)t * TMPD + 64 + l] + E2[i * TMPD + 64 + l];
        h0 = fmaxf(h0, 0.01f * h0);
        h1 = fmaxf(h1, 0.01f * h1);
        const double H0 = (double)h0, H1 = (double)h1;

        const unsigned char cc = ccnt[t];
        const bool lst = (cc <= (unsigned char)CMAX);
        const int cnt = lst ? (int)cc : 128;

        double best = -1.0e300; int bj = 0;
        for (int c = 0; c < cnt; ++c) {
            const int j = lst ? (int)clist[(size_t)t * CMAX + c] : c;
            const float* wr = W2Tf + (size_t)j * TMPD;
            double s = H0 * (double)wr[l] + H1 * (double)wr[64 + l];
            #pragma unroll
            for (int m = 1; m < 64; m <<= 1)
                s += __shfl_xor(s, m);
            s += (double)b2[j];
            if (s > best) { best = s; bj = j; }   // ascending j: ties -> lower j
        }
        if (l == 0) ftab[e] = (unsigned char)bj;
    }
}

// ---------------------------------------------------------------------------
// Serial repair sweep: only needed if the worklist overflowed.
// ---------------------------------------------------------------------------
__global__ void __launch_bounds__(128) repair_kernel(
    const float* __restrict__ pre, const float* __restrict__ E2,
    const float* __restrict__ W2,  const float* __restrict__ b2,
    const unsigned int* __restrict__ meta,
    unsigned char* __restrict__ ftab)
{
    if (meta[0] <= CAPW) return;
    const int j = threadIdx.x;

    __shared__ unsigned char frow[ED];
    __shared__ float  hbuf[TMPD];
    __shared__ double rvd[2];
    __shared__ int    ri[2];

    for (int tt = 0; tt < TPB; ++tt) {
        const int t = blockIdx.x * TPB + tt;
        const unsigned char fb = ftab[(size_t)t * ED + j];
        const int any = __syncthreads_or((int)(fb & 0x80));
        if (!any) continue;

        frow[j] = fb;
        __syncthreads();

        for (int i = 0; i < ED; ++i) {
            if (!(frow[i] & 0x80)) continue;
            const float f = pre[(size_t)t * TMPD + j] + E2[i * TMPD + j];
            hbuf[j] = fmaxf(f, 0.01f * f);
            __syncthreads();
            double a0 = 0.0, a1 = 0.0, a2 = 0.0, a3 = 0.0;
            #pragma unroll
            for (int k = 0; k < TMPD; k += 4) {
                a0 += (double)hbuf[k + 0] * (double)W2[(k + 0) * ED + j];
                a1 += (double)hbuf[k + 1] * (double)W2[(k + 1) * ED + j];
                a2 += (double)hbuf[k + 2] * (double)W2[(k + 2) * ED + j];
                a3 += (double)hbuf[k + 3] * (double)W2[(k + 3) * ED + j];
            }
            double mv = (double)b2[j] + ((a0 + a1) + (a2 + a3));
            int mi = j;
            #pragma unroll
            for (int m = 1; m < 64; m <<= 1) {
                const double ov = __shfl_xor(mv, m);
                const int    oi = __shfl_xor(mi, m);
                if (ov > mv || (ov == mv && oi < mi)) { mv = ov; mi = oi; }
            }
            if ((j & 63) == 0) { rvd[j >> 6] = mv; ri[j >> 6] = mi; }
            __syncthreads();
            int gi;
            if (rvd[1] > rvd[0] || (rvd[1] == rvd[0] && ri[1] < ri[0])) gi = ri[1];
            else gi = ri[0];
            if (j == 0) ftab[(size_t)t * ED + i] = (unsigned char)gi;
            __syncthreads();
        }
        __syncthreads();
    }
}

// ---------------------------------------------------------------------------
// Phase C: per-chunk hypothesis walk + compact final map.
// ---------------------------------------------------------------------------
__global__ void __launch_bounds__(128) walk_kernel(
    const unsigned char* __restrict__ ftab, unsigned char* __restrict__ walk,
    unsigned char* __restrict__ finmap)
{
    const int c   = blockIdx.x;
    const int tid = threadIdx.x;
    __shared__ unsigned char F[512 * 128];   // 64 KB

    const uint4* src = reinterpret_cast<const uint4*>(ftab + (size_t)c * 512 * 128);
    uint4* dst = reinterpret_cast<uint4*>(F);
    for (int e = tid; e < 512 * 128 / 16; e += 128) {
        uint4 v = src[e];
        v.x &= 0x7f7f7f7fu; v.y &= 0x7f7f7f7fu; v.z &= 0x7f7f7f7fu; v.w &= 0x7f7f7f7fu;
        dst[e] = v;
    }
    __syncthreads();

    int s = tid;
    unsigned char* wbase = walk + (size_t)c * 512 * 128;
    for (int tt = 0; tt < 512; ++tt) {
        s = F[tt * 128 + s];
        wbase[tt * 128 + tid] = (unsigned char)s;
    }
    finmap[c * 128 + tid] = (unsigned char)s;
}

__global__ void compose_kernel(const unsigned char* __restrict__ finmap,
                               const int* __restrict__ eidx,
                               unsigned char* __restrict__ echain)
{
    if (blockIdx.x == 0 && threadIdx.x == 0) {
        int e = eidx[0];
        for (int c = 0; c < 128; ++c) {
            echain[c] = (unsigned char)e;
            e = finmap[c * 128 + e];
        }
    }
}

// ---------------------------------------------------------------------------
// Phase D (MFMA): logp/emb/idx for all t. Block = 512 thr, 128 t.
// ---------------------------------------------------------------------------
__global__ void __launch_bounds__(512, 1) outm_kernel(
    const float* pre, const float* __restrict__ E2,
    const unsigned short* __restrict__ W2Th, const unsigned short* __restrict__ W2Tl,
    const float* __restrict__ b2,
    const unsigned char* __restrict__ walk, const unsigned char* __restrict__ echain,
    const float* __restrict__ emb,
    float* out_logp, float* __restrict__ out_emb, float* __restrict__ out_idx)
{
    const int tid = threadIdx.x;
    const int w   = tid >> 6;
    const int l   = tid & 63;
    const int ibase = (w >> 1) * 32;
    const int jhalf = w & 1;
    const int j0    = jhalf * 64;
    const int lc = l & 15, lg = l >> 4;
    const int t0 = blockIdx.x << 7;
    const int ec = echain[t0 >> 9];       // 128 | 512 -> constant per block

    __shared__ float smM[2][128];
    __shared__ float smS[2][128];
    __shared__ float smLSE[128];

    // B fragments
    bf16x8 Bh[4][4], Bl[4][4];
    #pragma unroll
    for (int jt = 0; jt < 4; ++jt)
        #pragma unroll
        for (int kk = 0; kk < 4; ++kk) {
            const int row = j0 + jt * 16 + lc;
            const int kof = kk * 32 + (lg << 3);
            Bh[jt][kk] = load_frag(W2Th + row * TMPD + kof);
            Bl[jt][kk] = load_frag(W2Tl + row * TMPD + kof);
        }
    float b2v[4];
    #pragma unroll
    for (int jt = 0; jt < 4; ++jt) b2v[jt] = b2[j0 + jt * 16 + lc];

    // previous state for this lane's two A-rows
    int si[2];
    #pragma unroll
    for (int it = 0; it < 2; ++it) {
        const int t = t0 + ibase + it * 16 + lc;
        si[it] = ((t & 511) == 0) ? ec : (int)walk[(size_t)(t - 1) * 128 + ec];
    }

    // ---- MFMA: logits = lrelu(PRE + E2[si]) @ W2 ----
    f32x4 acc[2][4];
    #pragma unroll
    for (int it = 0; it < 2; ++it)
        #pragma unroll
        for (int jt = 0; jt < 4; ++jt)
            acc[it][jt] = (f32x4){0.f, 0.f, 0.f, 0.f};

    #pragma unroll
    for (int kk = 0; kk < 4; ++kk) {
        const int kof = kk * 32 + (lg << 3);
        bf16x8 Ah[2], Al[2];
        #pragma unroll
        for (int it = 0; it < 2; ++it) {
            const float* pA = pre + (size_t)(t0 + ibase + it * 16 + lc) * TMPD + kof;
            const float* eA = E2 + (size_t)si[it] * TMPD + kof;
            const float4 p0 = *reinterpret_cast<const float4*>(pA);
            const float4 p1 = *reinterpret_cast<const float4*>(pA + 4);
            const float4 e0 = *reinterpret_cast<const float4*>(eA);
            const float4 e1 = *reinterpret_cast<const float4*>(eA + 4);
            split8(p0, p1, e0, e1, Ah[it], Al[it]);
        }
        #pragma unroll
        for (int it = 0; it < 2; ++it)
            #pragma unroll
            for (int jt = 0; jt < 4; ++jt) {
                acc[it][jt] = __builtin_amdgcn_mfma_f32_16x16x32_bf16(Al[it], Bh[jt][kk], acc[it][jt], 0, 0, 0);
                acc[it][jt] = __builtin_amdgcn_mfma_f32_16x16x32_bf16(Ah[it], Bl[jt][kk], acc[it][jt], 0, 0, 0);
                acc[it][jt] = __builtin_amdgcn_mfma_f32_16x16x32_bf16(Ah[it], Bh[jt][kk], acc[it][jt], 0, 0, 0);
            }
    }

    // ---- per-row max & sum over this wave's 64 j ----
    #pragma unroll
    for (int it = 0; it < 2; ++it) {
        #pragma unroll
        for (int r = 0; r < 4; ++r) {
            float v0 = acc[it][0][r] + b2v[0];
            float v1 = acc[it][1][r] + b2v[1];
            float v2 = acc[it][2][r] + b2v[2];
            float v3 = acc[it][3][r] + b2v[3];
            float mx = fmaxf(fmaxf(v0, v1), fmaxf(v2, v3));
            #pragma unroll
            for (int m = 1; m < 16; m <<= 1)
                mx = fmaxf(mx, __shfl_xor(mx, m));
            float s = expf(v0 - mx) + expf(v1 - mx) + expf(v2 - mx) + expf(v3 - mx);
            #pragma unroll
            for (int m = 1; m < 16; m <<= 1)
                s += __shfl_xor(s, m);
            if (lc == 0) {
                const int row = ibase + it * 16 + 4 * lg + r;
                smM[jhalf][row] = mx;
                smS[jhalf][row] = s;
            }
        }
    }
    __syncthreads();

    // ---- merge halves -> lse per row ----
    if (tid < 128) {
        const float m0 = smM[0][tid], m1 = smM[1][tid];
        const float s0 = smS[0][tid], s1 = smS[1][tid];
        const float m = fmaxf(m0, m1);
        smLSE[tid] = m + logf(s0 * expf(m0 - m) + s1 * expf(m1 - m));
    }
    __syncthreads();

    // ---- write logp ----
    #pragma unroll
    for (int it = 0; it < 2; ++it) {
        #pragma unroll
        for (int r = 0; r < 4; ++r) {
            const int row = ibase + it * 16 + 4 * lg + r;
            const float lse = smLSE[row];
            const int t = t0 + row;
            #pragma unroll
            for (int jt = 0; jt < 4; ++jt)
                out_logp[(size_t)t * TMPD + j0 + jt * 16 + lc] =
                    acc[it][jt][r] + b2v[jt] - lse;
        }
    }

    // ---- emb / idx ----
    if (tid < 128) {
        const int t  = t0 + tid;
        const int gi = walk[(size_t)t * 128 + ec];
        out_idx[t] = (float)gi;
        const float4* es = reinterpret_cast<const float4*>(emb + (size_t)gi * EMBD);
        float4*       ed = reinterpret_cast<float4*>(out_emb + (size_t)t * EMBD);
        #pragma unroll
        for (int q = 0; q < 4; ++q) ed[q] = es[q];
    }
}

// ---------------------------------------------------------------------------
// Fallback (ws too small): round-1 sequential kernel (known-good).
// ---------------------------------------------------------------------------
__global__ void __launch_bounds__(128, 1) seq_kernel(
    const float* pre_in, const int* __restrict__ eidx,
    const float* __restrict__ emb, const float* __restrict__ W1,
    const float* __restrict__ W2, const float* __restrict__ b2,
    float* out_logp, float* __restrict__ out_emb, float* __restrict__ out_idx)
{
    const int j = threadIdx.x;
    __shared__ float  E2s[ED * TMPD];
    __shared__ float  hbuf[TMPD];
    __shared__ double rvd[2];
    __shared__ int    ri[2];
    __shared__ float  rs[2];

    for (int i = 0; i < ED; ++i) {
        double a = 0.0;
        #pragma unroll
        for (int m = 0; m < EMBD; ++m)
            a += (double)emb[i * EMBD + m] * (double)W1[(HID + m) * TMPD + j];
        E2s[i * TMPD + j] = (float)a;
    }
    float w2c[TMPD];
    #pragma unroll 8
    for (int k = 0; k < TMPD; ++k) w2c[k] = W2[k * ED + j];
    const float bias2 = b2[j];
    int idx = eidx[0];
    __syncthreads();

    float pre_cur = pre_in[j];
    for (int t = 0; t < TT; ++t) {
        float pre_next = (t + 1 < TT) ? pre_in[(size_t)(t + 1) * TMPD + j] : 0.0f;
        float h = pre_cur + E2s[idx * TMPD + j];
        h = fmaxf(h, 0.01f * h);
        hbuf[j] = h;
        __syncthreads();
        double a0 = 0, a1 = 0, a2 = 0, a3 = 0;
        #pragma unroll
        for (int k = 0; k < TMPD; k += 4) {
            a0 += (double)hbuf[k + 0] * (double)w2c[k + 0];
            a1 += (double)hbuf[k + 1] * (double)w2c[k + 1];
            a2 += (double)hbuf[k + 2] * (double)w2c[k + 2];
            a3 += (double)hbuf[k + 3] * (double)w2c[k + 3];
        }
        const double logitd = (double)bias2 + ((a0 + a1) + (a2 + a3));
        const float  logit  = (float)logitd;
        double mv = logitd; int mi = j;
        #pragma unroll
        for (int m = 1; m < 64; m <<= 1) {
            double ov = __shfl_xor(mv, m);
            int    oi = __shfl_xor(mi, m);
            if (ov > mv || (ov == mv && oi < mi)) { mv = ov; mi = oi; }
        }
        if ((j & 63) == 0) { rvd[j >> 6] = mv; ri[j >> 6] = mi; }
        __syncthreads();
        int gi; double gmd;
        if (rvd[1] > rvd[0] || (rvd[1] == rvd[0] && ri[1] < ri[0])) { gmd = rvd[1]; gi = ri[1]; }
        else { gmd = rvd[0]; gi = ri[0]; }
        const float gm = (float)gmd;
        float e = expf(logit - gm);
        float s = e;
        #pragma unroll
        for (int m = 1; m < 64; m <<= 1) s += __shfl_xor(s, m);
        if ((j & 63) == 0) rs[j >> 6] = s;
        __syncthreads();
        const float lse = gm + logf(rs[0] + rs[1]);
        out_logp[(size_t)t * TMPD + j] = logit - lse;
        if (j < EMBD) out_emb[(size_t)t * EMBD + j] = emb[gi * EMBD + j];
        if (j == 0)   out_idx[t] = (float)gi;
        idx = gi;
        pre_cur = pre_next;
        __syncthreads();
    }
}

// ---------------------------------------------------------------------------
extern "C" void kernel_launch(void* const* d_in, const int* in_sizes, int n_in,
                              void* d_out, int out_size, void* d_ws, size_t ws_size,
                              hipStream_t stream)
{
    const float* x    = (const float*)d_in[0];
    const int*   eidx = (const int*)  d_in[1];
    const float* emb  = (const float*)d_in[2];
    const float* W1   = (const float*)d_in[3];
    const float* b1   = (const float*)d_in[4];
    const float* W2   = (const float*)d_in[5];
    const float* b2   = (const float*)d_in[6];

    float* out0 = (float*)d_out;                 // logp  (T*128) = 32 MB
    float* out1 = out0 + (size_t)TT * TMPD;      // emb   (T*16)
    float* out2 = out1 + (size_t)TT * EMBD;      // index (T)

    // ---- workspace layout ----
    const size_t OFF_E2    = 0;                          // 64 KB
    const size_t OFF_E2T4  = OFF_E2    + 64 * 1024;      // 64 KB
    const size_t OFF_W2TH  = OFF_E2T4  + 64 * 1024;      // 32 KB
    const size_t OFF_W2TL  = OFF_W2TH  + 32 * 1024;      // 32 KB
    const size_t OFF_W2TF  = OFF_W2TL  + 32 * 1024;      // 64 KB
    const size_t OFF_DP    = OFF_W2TF  + 64 * 1024;      // 4 KB
    const size_t OFF_META  = OFF_DP    + 4 * 1024;       // 4 KB
    const size_t OFF_FLAG  = OFF_META  + 4 * 1024;       // 4 KB (probe flag)
    const size_t OFF_W1D   = OFF_FLAG  + 4 * 1024;       // 256 KB (W1 in fp64)
    const size_t OFF_CCNT  = OFF_W1D   + 256 * 1024;     // 64 KB
    const size_t OFF_ECHN  = OFF_CCNT  + 64 * 1024;      // 4 KB
    const size_t OFF_FIN   = OFF_ECHN  + 4 * 1024;       // 16 KB
    const size_t OFF_TLIST = OFF_FIN   + 16 * 1024;      // 256 KB
    const size_t OFF_CLIST = OFF_TLIST + 256 * 1024;     // 2 MB
    const size_t OFF_FTAB  = OFF_CLIST + 2048 * 1024;    // 8 MB
    const size_t OFF_WALK  = OFF_FTAB  + (size_t)TT * ED;        // 8 MB
    const size_t OFF_WORK  = OFF_WALK  + (size_t)TT * ED;        // 4 MB
    const size_t AUXN      = OFF_WORK  + (size_t)CAPW * 4;
    const size_t PRE_B     = (size_t)TT * TMPD * sizeof(float);  // 32 MB

    unsigned char* wsb = (unsigned char*)d_ws;
    float*          E2    = (float*)(wsb + OFF_E2);
    float*          E2T4  = (float*)(wsb + OFF_E2T4);
    unsigned short* W2Th  = (unsigned short*)(wsb + OFF_W2TH);
    unsigned short* W2Tl  = (unsigned short*)(wsb + OFF_W2TL);
    float*          W2Tf  = (float*)(wsb + OFF_W2TF);
    float*          Dp    = (float*)(wsb + OFF_DP);
    unsigned int*   meta  = (unsigned int*)(wsb + OFF_META);
    unsigned int*   pflag = (unsigned int*)(wsb + OFF_FLAG);
    double*         W1d   = (double*)(wsb + OFF_W1D);
    unsigned char*  ccnt  = wsb + OFF_CCNT;
    unsigned char*  echn  = wsb + OFF_ECHN;
    unsigned char*  fin   = wsb + OFF_FIN;
    unsigned int*   tlist = (unsigned int*)(wsb + OFF_TLIST);
    unsigned char*  clist = wsb + OFF_CLIST;
    unsigned char*  ftab  = wsb + OFF_FTAB;
    unsigned char*  walk  = wsb + OFF_WALK;
    unsigned int*   work  = (unsigned int*)(wsb + OFF_WORK);

    if (ws_size >= AUXN) {
        float* pre = (ws_size >= AUXN + PRE_B) ? (float*)(wsb + AUXN) : out0;

        w1d_kernel    <<<128,      256, 0, stream>>>(W1, W1d);
        probe_kernel  <<<1,         64, 0, stream>>>(pflag);
        prem_kernel   <<<TT / 16,  512, 0, stream>>>(x, W1d, b1, pre, pflag);
        prev_kernel   <<<TT / 16,  128, 0, stream>>>(x, W1d, b1, pre, pflag);
        w2split_kernel<<<64,       256, 0, stream>>>(W2, W2Th, W2Tl, W2Tf);
        e2z_kernel    <<<128,      128, 0, stream>>>(emb, W1, E2, E2T4, meta);
        dp_kernel     <<<128,      128, 0, stream>>>(E2, W2Tf, Dp);
        l0_kernel     <<<TT / 128, 512, 0, stream>>>(pre, W2Th, W2Tl, b2, Dp,
                                                     ftab, clist, ccnt, tlist, meta);
        tier2_kernel  <<<4096,     128, 0, stream>>>(pre, E2T4, W2Tf, b2, meta,
                                                     tlist, ccnt, clist, ftab);
        compact_kernel<<<TT * ED / 4 / 256, 256, 0, stream>>>(ftab, meta, work);
        repair3_kernel<<<8192,      64, 0, stream>>>(pre, E2, W2Tf, b2, clist,
                                                     ccnt, meta, work, ftab);
        repair_kernel <<<TT / TPB, 128, 0, stream>>>(pre, E2, W2, b2, meta, ftab);
        walk_kernel   <<<TT / 512, 128, 0, stream>>>(ftab, walk, fin);
        compose_kernel<<<1,         64, 0, stream>>>(fin, eidx, echn);
        outm_kernel   <<<TT / 128, 512, 0, stream>>>(pre, E2, W2Th, W2Tl, b2,
                                                     walk, echn, emb,
                                                     out0, out1, out2);
    } else {
        float* pre2 = (ws_size >= PRE_B) ? (float*)d_ws : out0;
        preold_kernel<<<TT / 16, 128, 0, stream>>>(x, W1, b1, pre2);
        seq_kernel<<<1, 128, 0, stream>>>(pre2, eidx, emb, W1, W2, b2,
                                          out0, out1, out2);
    }
}

// Round 15
// 419.120 us; speedup vs baseline: 1.2731x; 1.2731x over previous
//
#include <hip/hip_runtime.h>

#define TT   65536
#define HID  256
#define EMBD 16
#define TMPD 128   // hidden layer width (TMP) == K of second GEMM
#define ED   128   // EVENT_DIM
#define TAU  5e-4f
#define EPS  1e-3f
#define NEGINF (-3.402823466e38f)
#define TPB  32            // timesteps per block (repair sweep)
#define CAPW (1u << 20)    // worklist capacity (1M entries)
#define CMAX 24
#define TPRE 32            // timesteps per pre block
#define XSP2 258           // x LDS pitch (floats)

typedef __bf16  bf16x8 __attribute__((ext_vector_type(8)));
typedef float   f32x4  __attribute__((ext_vector_type(4)));
typedef short   s16x8  __attribute__((ext_vector_type(8)));

__device__ inline unsigned short f2bf(float f) {
    __bf16 b = (__bf16)f;
    return __builtin_bit_cast(unsigned short, b);
}
__device__ inline float bf2f(unsigned short u) {
    unsigned int x = ((unsigned int)u) << 16;
    return __builtin_bit_cast(float, x);
}
__device__ inline bf16x8 load_frag(const unsigned short* p) {
    uint4 r = *reinterpret_cast<const uint4*>(p);
    return __builtin_bit_cast(bf16x8, r);
}
// h = lrelu(p+e); split to bf16 hi/lo
__device__ inline void split8(const float4& p0, const float4& p1,
                              const float4& e0, const float4& e1,
                              bf16x8& hi, bf16x8& lo)
{
    const float f[8] = {p0.x + e0.x, p0.y + e0.y, p0.z + e0.z, p0.w + e0.w,
                        p1.x + e1.x, p1.y + e1.y, p1.z + e1.z, p1.w + e1.w};
    s16x8 hs, ls;
    #pragma unroll
    for (int q = 0; q < 8; ++q) {
        const float h = fmaxf(f[q], 0.01f * f[q]);
        const unsigned short hb = f2bf(h);
        hs[q] = (short)hb;
        ls[q] = (short)f2bf(h - bf2f(hb));
    }
    hi = __builtin_bit_cast(bf16x8, hs);
    lo = __builtin_bit_cast(bf16x8, ls);
}

// ---------------------------------------------------------------------------
// Phase A: PRE[t][j] = b1[j] + sum_k x[t][k]*W1[k][j]   (fp64 accum).
// Register-tiled: 256 thr, 32 t/block; thread (tg,jg) owns 4t x 4j.
// Per k: 1 float4 W1 load + 4 LDS broadcasts -> 16 fp64 FMAs.
// ---------------------------------------------------------------------------
__global__ void __launch_bounds__(256) pre_kernel(const float* __restrict__ x,
                                                  const float* __restrict__ W1,
                                                  const float* __restrict__ b1,
                                                  float* __restrict__ pre)
{
    const int tid = threadIdx.x;
    const int jg  = tid & 31;          // j-group: columns 4*jg..4*jg+3
    const int tg  = tid >> 5;          // 0..7 -> t rows 4*tg..4*tg+3
    const int t0  = blockIdx.x * TPRE;
    const int jb  = jg * 4;

    __shared__ float xs[TPRE * XSP2];  // 33 KB

    for (int e = tid; e < TPRE * HID; e += 256)
        xs[(e >> 8) * XSP2 + (e & 255)] = x[(size_t)t0 * HID + e];
    __syncthreads();

    double acc[4][4];
    #pragma unroll
    for (int tt = 0; tt < 4; ++tt)
        #pragma unroll
        for (int jj = 0; jj < 4; ++jj) acc[tt][jj] = 0.0;

    const float* xrow = xs + (4 * tg) * XSP2;
    #pragma unroll 2
    for (int k = 0; k < HID; ++k) {
        const float4 w4 = *reinterpret_cast<const float4*>(&W1[k * TMPD + jb]);
        const double w0 = (double)w4.x, w1 = (double)w4.y;
        const double w2 = (double)w4.z, w3 = (double)w4.w;
        #pragma unroll
        for (int tt = 0; tt < 4; ++tt) {
            const double xv = (double)xrow[tt * XSP2 + k];
            acc[tt][0] = fma(xv, w0, acc[tt][0]);
            acc[tt][1] = fma(xv, w1, acc[tt][1]);
            acc[tt][2] = fma(xv, w2, acc[tt][2]);
            acc[tt][3] = fma(xv, w3, acc[tt][3]);
        }
    }

    double bb[4];
    #pragma unroll
    for (int jj = 0; jj < 4; ++jj) bb[jj] = (double)b1[jb + jj];
    #pragma unroll
    for (int tt = 0; tt < 4; ++tt) {
        const size_t row = (size_t)(t0 + 4 * tg + tt) * TMPD + jb;
        #pragma unroll
        for (int jj = 0; jj < 4; ++jj)
            pre[row + jj] = (float)(acc[tt][jj] + bb[jj]);
    }
}

// ---------------------------------------------------------------------------
// Simple PRE (small-ws fallback path; round-12 known-good).
// ---------------------------------------------------------------------------
__global__ void __launch_bounds__(128) preold_kernel(const float* __restrict__ x,
                                                     const float* __restrict__ W1,
                                                     const float* __restrict__ b1,
                                                     float* __restrict__ pre)
{
    const int j  = threadIdx.x;
    const int t0 = blockIdx.x * 16;

    __shared__ float xs[16 * HID];
    for (int i = j; i < 16 * HID; i += 128)
        xs[i] = x[(size_t)t0 * HID + i];
    __syncthreads();

    double acc[16];
    #pragma unroll
    for (int tt = 0; tt < 16; ++tt) acc[tt] = 0.0;

    #pragma unroll 4
    for (int k = 0; k < HID; ++k) {
        const double w = (double)W1[k * TMPD + j];
        #pragma unroll
        for (int tt = 0; tt < 16; ++tt)
            acc[tt] += (double)xs[tt * HID + k] * w;
    }
    const double bb = (double)b1[j];
    #pragma unroll
    for (int tt = 0; tt < 16; ++tt)
        pre[(size_t)(t0 + tt) * TMPD + j] = (float)(bb + acc[tt]);
}

// ---------------------------------------------------------------------------
// W2 split (parallel): one (k,j) element per thread.
// ---------------------------------------------------------------------------
__global__ void __launch_bounds__(256) w2split_kernel(
    const float* __restrict__ W2,
    unsigned short* __restrict__ W2Th, unsigned short* __restrict__ W2Tl,
    float* __restrict__ W2Tf)
{
    const int gid = blockIdx.x * 256 + threadIdx.x;
    const int k = gid >> 7, j = gid & 127;
    const float v = W2[k * ED + j];
    const unsigned short hi = f2bf(v);
    const unsigned short lo = f2bf(v - bf2f(hi));
    W2Th[j * TMPD + k] = hi;
    W2Tl[j * TMPD + k] = lo;
    W2Tf[j * TMPD + k] = v;
}

// ---------------------------------------------------------------------------
// E2 (parallel, fp64 identical math) + E2T4 (k-quad packed) + zero meta.
// ---------------------------------------------------------------------------
__global__ void __launch_bounds__(128) e2z_kernel(
    const float* __restrict__ emb, const float* __restrict__ W1,
    float* __restrict__ E2, float* __restrict__ E2T4,
    unsigned int* __restrict__ meta)
{
    const int i = blockIdx.x;
    const int j = threadIdx.x;
    if (i == 0 && j < 8) meta[j] = 0;
    double a = 0.0;
    #pragma unroll
    for (int m = 0; m < EMBD; ++m)
        a += (double)emb[i * EMBD + m] * (double)W1[(HID + m) * TMPD + j];
    const float v = (float)a;
    E2[i * TMPD + j] = v;
    E2T4[(j >> 2) * 512 + i * 4 + (j & 3)] = v;
}

// ---------------------------------------------------------------------------
// Dp (parallel): block j, thread i, max-reduce over i.
// ---------------------------------------------------------------------------
__global__ void __launch_bounds__(128) dp_kernel(
    const float* __restrict__ E2, const float* __restrict__ W2Tf,
    float* __restrict__ Dp)
{
    const int j = blockIdx.x;
    const int i = threadIdx.x;
    __shared__ float red[2];

    const float* e2r = E2 + (size_t)i * TMPD;
    const float* w2r = W2Tf + (size_t)j * TMPD;
    float s = 0.f;
    #pragma unroll 4
    for (int k = 0; k < TMPD; ++k)
        s = fmaf(fabsf(e2r[k]), fabsf(w2r[k]), s);

    #pragma unroll
    for (int m = 1; m < 64; m <<= 1)
        s = fmaxf(s, __shfl_xor(s, m));
    if ((i & 63) == 0) red[i >> 6] = s;
    __syncthreads();
    if (i == 0) Dp[j] = fmaxf(red[0], red[1]) * 1.0001f + 1e-6f;
}

// ---------------------------------------------------------------------------
// L0 + classification. Block = 512 thr (8 waves), 128 t rows, all 128 j.
// ---------------------------------------------------------------------------
__global__ void __launch_bounds__(512, 1) l0_kernel(
    const float* __restrict__ pre,
    const unsigned short* __restrict__ W2Th, const unsigned short* __restrict__ W2Tl,
    const float* __restrict__ b2, const float* __restrict__ Dp,
    unsigned char* __restrict__ ftab,
    unsigned char* __restrict__ clist, unsigned char* __restrict__ ccnt,
    unsigned int* __restrict__ tlist, unsigned int* __restrict__ meta)
{
    const int tid = threadIdx.x;
    const int w   = tid >> 6;
    const int l   = tid & 63;
    const int ibase = (w >> 1) * 32;
    const int jhalf = w & 1;
    const int j0    = jhalf * 64;
    const int lc = l & 15, lg = l >> 4;
    const int t0 = blockIdx.x << 7;

    __shared__ float smA [2][128];
    __shared__ int   smAX[2][128];
    __shared__ float smW1[2][128];
    __shared__ int   smWX[2][128];
    __shared__ float smW2[2][128];
    __shared__ unsigned long long smMask[2][128];
    __shared__ float smThr[128];
    __shared__ int   smJ[128];

    // B fragments
    bf16x8 Bh[4][4], Bl[4][4];
    #pragma unroll
    for (int jt = 0; jt < 4; ++jt)
        #pragma unroll
        for (int kk = 0; kk < 4; ++kk) {
            const int row = j0 + jt * 16 + lc;
            const int kof = kk * 32 + (lg << 3);
            Bh[jt][kk] = load_frag(W2Th + row * TMPD + kof);
            Bl[jt][kk] = load_frag(W2Tl + row * TMPD + kof);
        }
    float b2v[4], dpv[4];
    #pragma unroll
    for (int jt = 0; jt < 4; ++jt) {
        b2v[jt] = b2[j0 + jt * 16 + lc];
        dpv[jt] = Dp[j0 + jt * 16 + lc];
    }

    // ---- MFMA: L0 = lrelu(PRE) @ W2 (split-bf16 3-pass) ----
    f32x4 acc[2][4];
    #pragma unroll
    for (int it = 0; it < 2; ++it)
        #pragma unroll
        for (int jt = 0; jt < 4; ++jt)
            acc[it][jt] = (f32x4){0.f, 0.f, 0.f, 0.f};

    const float4 z4 = {0.f, 0.f, 0.f, 0.f};
    #pragma unroll
    for (int kk = 0; kk < 4; ++kk) {
        const int kof = kk * 32 + (lg << 3);
        bf16x8 Ah[2], Al[2];
        #pragma unroll
        for (int it = 0; it < 2; ++it) {
            const float* pA = pre + (size_t)(t0 + ibase + it * 16 + lc) * TMPD + kof;
            const float4 p0 = *reinterpret_cast<const float4*>(pA);
            const float4 p1 = *reinterpret_cast<const float4*>(pA + 4);
            split8(p0, p1, z4, z4, Ah[it], Al[it]);
        }
        #pragma unroll
        for (int it = 0; it < 2; ++it)
            #pragma unroll
            for (int jt = 0; jt < 4; ++jt) {
                acc[it][jt] = __builtin_amdgcn_mfma_f32_16x16x32_bf16(Al[it], Bh[jt][kk], acc[it][jt], 0, 0, 0);
                acc[it][jt] = __builtin_amdgcn_mfma_f32_16x16x32_bf16(Ah[it], Bl[jt][kk], acc[it][jt], 0, 0, 0);
                acc[it][jt] = __builtin_amdgcn_mfma_f32_16x16x32_bf16(Ah[it], Bh[jt][kk], acc[it][jt], 0, 0, 0);
            }
    }

    // ---- pass 1: per-row A-top1/argmax and W-top2 within this half ----
    #pragma unroll
    for (int it = 0; it < 2; ++it) {
        #pragma unroll
        for (int r = 0; r < 4; ++r) {
            float av0 = acc[it][0][r] + b2v[0];
            float a1 = av0; int x1 = j0 + lc;
            float w1 = av0 + dpv[0]; int wx1 = j0 + lc; float w2 = NEGINF;
            #pragma unroll
            for (int jt = 1; jt < 4; ++jt) {
                const float av = acc[it][jt][r] + b2v[jt];
                const int   jj = j0 + jt * 16 + lc;
                if (av > a1) { a1 = av; x1 = jj; }
                const float wv = av + dpv[jt];
                if (wv > w1) { w2 = w1; w1 = wv; wx1 = jj; }
                else         { w2 = fmaxf(w2, wv); }
            }
            #pragma unroll
            for (int m = 1; m < 16; m <<= 1) {
                const float oa = __shfl_xor(a1, m);
                const int   ox = __shfl_xor(x1, m);
                if (oa > a1 || (oa == a1 && ox < x1)) { a1 = oa; x1 = ox; }
                const float ow1 = __shfl_xor(w1, m);
                const int   owx = __shfl_xor(wx1, m);
                const float ow2 = __shfl_xor(w2, m);
                const bool take = (ow1 > w1) || (ow1 == w1 && owx < wx1);
                const float loser = take ? w1 : ow1;
                w2 = fmaxf(w2, fmaxf(ow2, loser));
                if (take) { w1 = ow1; wx1 = owx; }
            }
            if (lc == 0) {
                const int row = ibase + it * 16 + 4 * lg + r;
                smA [jhalf][row] = a1;  smAX[jhalf][row] = x1;
                smW1[jhalf][row] = w1;  smWX[jhalf][row] = wx1;
                smW2[jhalf][row] = w2;
            }
        }
    }
    __syncthreads();

    // ---- merge 1: singleton test ----
    if (tid < 128) {
        const int row = tid, t = t0 + row;
        const float A0 = smA[0][row], A1 = smA[1][row];
        const int   X0 = smAX[0][row], X1 = smAX[1][row];
        const bool  h1 = (A1 > A0);
        const float astar = h1 ? A1 : A0;
        const int   jstar = h1 ? X1 : X0;
        const float c0 = (smWX[0][row] == jstar) ? smW2[0][row] : smW1[0][row];
        const float c1 = (smWX[1][row] == jstar) ? smW2[1][row] : smW1[1][row];
        const float M2 = fmaxf(c0, c1);
        const float thr = astar - Dp[jstar] - EPS;
        smJ[row] = jstar;
        if (thr > M2) {      // provably constant transition for all i
            smThr[row] = 3.0e38f;
            const unsigned int q = (unsigned int)jstar * 0x01010101u;
            const uint4 qv = make_uint4(q, q, q, q);
            uint4* dst = reinterpret_cast<uint4*>(ftab + (size_t)t * ED);
            #pragma unroll
            for (int u = 0; u < 8; ++u) dst[u] = qv;
        } else {
            smThr[row] = thr;
        }
    }
    __syncthreads();

    // ---- pass 2: candidate ballot (W_j >= thr) ----
    #pragma unroll
    for (int it = 0; it < 2; ++it) {
        #pragma unroll
        for (int r = 0; r < 4; ++r) {
            const int row = ibase + it * 16 + 4 * lg + r;
            const float thr = smThr[row];
            unsigned long long mask = 0ull;
            #pragma unroll
            for (int jt = 0; jt < 4; ++jt) {
                const float wv = acc[it][jt][r] + b2v[jt] + dpv[jt];
                const unsigned long long b = __ballot(wv >= thr);
                mask |= ((b >> (lg * 16)) & 0xFFFFull) << (jt * 16);
            }
            if (lc == 0) smMask[jhalf][row] = mask;
        }
    }
    __syncthreads();

    // ---- merge 2: extract candidates ----
    if (tid < 128) {
        const int row = tid, t = t0 + row;
        const float thr = smThr[row];
        if (thr < 1e38f) {
            unsigned long long m0 = smMask[0][row], m1 = smMask[1][row];
            const int cnt = __popcll(m0) + __popcll(m1);
            if (cnt > CMAX) {   // rare: flag whole t for full fp64 repair
                ccnt[t] = 0xFFu;
                const unsigned int q = ((unsigned int)smJ[row] | 0x80u) * 0x01010101u;
                const uint4 qv = make_uint4(q, q, q, q);
                uint4* dst = reinterpret_cast<uint4*>(ftab + (size_t)t * ED);
                #pragma unroll
                for (int u = 0; u < 8; ++u) dst[u] = qv;
            } else {
                int c = 0;
                while (m0) { const int b = __ffsll((unsigned long long)m0) - 1;
                             clist[(size_t)t * CMAX + c] = (unsigned char)b; ++c; m0 &= m0 - 1; }
                while (m1) { const int b = __ffsll((unsigned long long)m1) - 1;
                             clist[(size_t)t * CMAX + c] = (unsigned char)(64 + b); ++c; m1 &= m1 - 1; }
                ccnt[t] = (unsigned char)cnt;
                const unsigned int pos = atomicAdd(&meta[1], 1u);
                tlist[pos] = (unsigned int)t;
            }
        }
    }
}

// ---------------------------------------------------------------------------
// Tier-2 v5: E2T4 k-quad packed, float4 broadcast reads, cnt-adaptive width.
// ---------------------------------------------------------------------------
__global__ void __launch_bounds__(128) tier2_kernel(
    const float* __restrict__ pre, const float* __restrict__ E2T4,
    const float* __restrict__ W2Tf, const float* __restrict__ b2,
    const unsigned int* __restrict__ meta,
    const unsigned int* __restrict__ tlist, const unsigned char* __restrict__ ccnt,
    const unsigned char* __restrict__ clist, unsigned char* __restrict__ ftab)
{
    const int i = threadIdx.x;
    __shared__ float Ps[TMPD];
    __shared__ float Ws[8][TMPD];
    __shared__ float vb[8];
    __shared__ unsigned char clj[CMAX];
    __shared__ int scnt;

    const float4* e4p = reinterpret_cast<const float4*>(E2T4) + i;  // +kq*128

    const unsigned int n2 = meta[1];
    for (unsigned int u = blockIdx.x; u < n2; u += gridDim.x) {
        const int t = (int)tlist[u];
        if (i == 0) scnt = (int)ccnt[t];
        Ps[i] = pre[(size_t)t * TMPD + i];
        if (i < CMAX) clj[i] = clist[(size_t)t * CMAX + i];
        __syncthreads();                                   // A
        const int cnt = scnt;

        float t1 = NEGINF, t2 = NEGINF; int x1 = 0;
        for (int g0 = 0; g0 < cnt; g0 += 8) {
            const int gn = min(8, cnt - g0);
            for (int c = 0; c < gn; ++c)
                Ws[c][i] = W2Tf[(int)clj[g0 + c] * TMPD + i];
            if (i < 8) vb[i] = (i < gn) ? b2[clj[g0 + i]] : NEGINF;
            __syncthreads();                               // B

            float s[8] = {0.f, 0.f, 0.f, 0.f, 0.f, 0.f, 0.f, 0.f};
            if (gn <= 2) {
                #pragma unroll 4
                for (int kq = 0; kq < 32; ++kq) {
                    const float4 e4 = e4p[kq * ED];
                    const float4 p4 = *reinterpret_cast<const float4*>(&Ps[4 * kq]);
                    const float4 w0 = *reinterpret_cast<const float4*>(&Ws[0][4 * kq]);
                    const float4 w1 = *reinterpret_cast<const float4*>(&Ws[1][4 * kq]);
                    float h;
                    h = p4.x + e4.x; h = fmaxf(h, 0.01f * h);
                    s[0] = fmaf(h, w0.x, s[0]); s[1] = fmaf(h, w1.x, s[1]);
                    h = p4.y + e4.y; h = fmaxf(h, 0.01f * h);
                    s[0] = fmaf(h, w0.y, s[0]); s[1] = fmaf(h, w1.y, s[1]);
                    h = p4.z + e4.z; h = fmaxf(h, 0.01f * h);
                    s[0] = fmaf(h, w0.z, s[0]); s[1] = fmaf(h, w1.z, s[1]);
                    h = p4.w + e4.w; h = fmaxf(h, 0.01f * h);
                    s[0] = fmaf(h, w0.w, s[0]); s[1] = fmaf(h, w1.w, s[1]);
                }
            } else if (gn <= 4) {
                #pragma unroll 2
                for (int kq = 0; kq < 32; ++kq) {
                    const float4 e4 = e4p[kq * ED];
                    const float4 p4 = *reinterpret_cast<const float4*>(&Ps[4 * kq]);
                    const float4 w0 = *reinterpret_cast<const float4*>(&Ws[0][4 * kq]);
                    const float4 w1 = *reinterpret_cast<const float4*>(&Ws[1][4 * kq]);
                    const float4 w2 = *reinterpret_cast<const float4*>(&Ws[2][4 * kq]);
                    const float4 w3 = *reinterpret_cast<const float4*>(&Ws[3][4 * kq]);
                    float h;
                    h = p4.x + e4.x; h = fmaxf(h, 0.01f * h);
                    s[0] = fmaf(h, w0.x, s[0]); s[1] = fmaf(h, w1.x, s[1]);
                    s[2] = fmaf(h, w2.x, s[2]); s[3] = fmaf(h, w3.x, s[3]);
                    h = p4.y + e4.y; h = fmaxf(h, 0.01f * h);
                    s[0] = fmaf(h, w0.y, s[0]); s[1] = fmaf(h, w1.y, s[1]);
                    s[2] = fmaf(h, w2.y, s[2]); s[3] = fmaf(h, w3.y, s[3]);
                    h = p4.z + e4.z; h = fmaxf(h, 0.01f * h);
                    s[0] = fmaf(h, w0.z, s[0]); s[1] = fmaf(h, w1.z, s[1]);
                    s[2] = fmaf(h, w2.z, s[2]); s[3] = fmaf(h, w3.z, s[3]);
                    h = p4.w + e4.w; h = fmaxf(h, 0.01f * h);
                    s[0] = fmaf(h, w0.w, s[0]); s[1] = fmaf(h, w1.w, s[1]);
                    s[2] = fmaf(h, w2.w, s[2]); s[3] = fmaf(h, w3.w, s[3]);
                }
            } else {
                for (int kq = 0; kq < 32; ++kq) {
                    const float4 e4 = e4p[kq * ED];
                    const float4 p4 = *reinterpret_cast<const float4*>(&Ps[4 * kq]);
                    float4 wc[8];
                    #pragma unroll
                    for (int c = 0; c < 8; ++c)
                        wc[c] = *reinterpret_cast<const float4*>(&Ws[c][4 * kq]);
                    float h;
                    h = p4.x + e4.x; h = fmaxf(h, 0.01f * h);
                    #pragma unroll
                    for (int c = 0; c < 8; ++c) s[c] = fmaf(h, wc[c].x, s[c]);
                    h = p4.y + e4.y; h = fmaxf(h, 0.01f * h);
                    #pragma unroll
                    for (int c = 0; c < 8; ++c) s[c] = fmaf(h, wc[c].y, s[c]);
                    h = p4.z + e4.z; h = fmaxf(h, 0.01f * h);
                    #pragma unroll
                    for (int c = 0; c < 8; ++c) s[c] = fmaf(h, wc[c].z, s[c]);
                    h = p4.w + e4.w; h = fmaxf(h, 0.01f * h);
                    #pragma unroll
                    for (int c = 0; c < 8; ++c) s[c] = fmaf(h, wc[c].w, s[c]);
                }
            }

            for (int c = 0; c < gn; ++c) {
                const float v = s[c] + vb[c];
                const int jj = (int)clj[g0 + c];
                if (v > t1) { t2 = t1; t1 = v; x1 = jj; }
                else        { t2 = fmaxf(t2, v); }
            }
            __syncthreads();                               // C
        }
        unsigned char byte = (unsigned char)x1;
        if (t1 - t2 < TAU) byte |= 0x80u;
        ftab[(size_t)t * ED + i] = byte;
        __syncthreads();                                   // D
    }
}

// ---------------------------------------------------------------------------
// Compact flagged (t,i) byte-indices into a worklist.
// ---------------------------------------------------------------------------
__global__ void __launch_bounds__(256) compact_kernel(
    const unsigned char* __restrict__ ftab,
    unsigned int* __restrict__ meta, unsigned int* __restrict__ work)
{
    const unsigned int gid = blockIdx.x * 256 + threadIdx.x;
    const unsigned int v = reinterpret_cast<const unsigned int*>(ftab)[gid];
    const unsigned int flags = v & 0x80808080u;
    if (flags) {
        const int cnt = __popc(flags);
        unsigned int base = atomicAdd(meta, (unsigned int)cnt);
        #pragma unroll
        for (int b = 0; b < 4; ++b)
            if (v & (0x80u << (8 * b))) {
                if (base < CAPW) work[base] = gid * 4 + b;
                ++base;
            }
    }
}

// ---------------------------------------------------------------------------
// Candidate repair: one wave per flagged (t,i); fp64 logits only for j in C.
// ---------------------------------------------------------------------------
__global__ void __launch_bounds__(64) repair3_kernel(
    const float* __restrict__ pre, const float* __restrict__ E2,
    const float* __restrict__ W2Tf, const float* __restrict__ b2,
    const unsigned char* __restrict__ clist, const unsigned char* __restrict__ ccnt,
    const unsigned int* __restrict__ meta, const unsigned int* __restrict__ work,
    unsigned char* __restrict__ ftab)
{
    const int l = threadIdx.x;   // 0..63
    unsigned int n = meta[0];
    if (n > CAPW) n = CAPW;

    for (unsigned int u = blockIdx.x; u < n; u += gridDim.x) {
        const unsigned int e = work[u];
        const int t = (int)(e >> 7), i = (int)(e & 127u);

        float h0 = pre[(size_t)t * TMPD + l]      + E2[i * TMPD + l];
        float h1 = pre[(size_t)t * TMPD + 64 + l] + E2[i * TMPD + 64 + l];
        h0 = fmaxf(h0, 0.01f * h0);
        h1 = fmaxf(h1, 0.01f * h1);
        const double H0 = (double)h0, H1 = (double)h1;

        const unsigned char cc = ccnt[t];
        const bool lst = (cc <= (unsigned char)CMAX);
        const int cnt = lst ? (int)cc : 128;

        double best = -1.0e300; int bj = 0;
        for (int c = 0; c < cnt; ++c) {
            const int j = lst ? (int)clist[(size_t)t * CMAX + c] : c;
            const float* wr = W2Tf + (size_t)j * TMPD;
            double s = H0 * (double)wr[l] + H1 * (double)wr[64 + l];
            #pragma unroll
            for (int m = 1; m < 64; m <<= 1)
                s += __shfl_xor(s, m);
            s += (double)b2[j];
            if (s > best) { best = s; bj = j; }   // ascending j: ties -> lower j
        }
        if (l == 0) ftab[e] = (unsigned char)bj;
    }
}

// ---------------------------------------------------------------------------
// Serial repair sweep: only needed if the worklist overflowed.
// ---------------------------------------------------------------------------
__global__ void __launch_bounds__(128) repair_kernel(
    const float* __restrict__ pre, const float* __restrict__ E2,
    const float* __restrict__ W2,  const float* __restrict__ b2,
    const unsigned int* __restrict__ meta,
    unsigned char* __restrict__ ftab)
{
    if (meta[0] <= CAPW) return;
    const int j = threadIdx.x;

    __shared__ unsigned char frow[ED];
    __shared__ float  hbuf[TMPD];
    __shared__ double rvd[2];
    __shared__ int    ri[2];

    for (int tt = 0; tt < TPB; ++tt) {
        const int t = blockIdx.x * TPB + tt;
        const unsigned char fb = ftab[(size_t)t * ED + j];
        const int any = __syncthreads_or((int)(fb & 0x80));
        if (!any) continue;

        frow[j] = fb;
        __syncthreads();

        for (int i = 0; i < ED; ++i) {
            if (!(frow[i] & 0x80)) continue;
            const float f = pre[(size_t)t * TMPD + j] + E2[i * TMPD + j];
            hbuf[j] = fmaxf(f, 0.01f * f);
            __syncthreads();
            double a0 = 0.0, a1 = 0.0, a2 = 0.0, a3 = 0.0;
            #pragma unroll
            for (int k = 0; k < TMPD; k += 4) {
                a0 += (double)hbuf[k + 0] * (double)W2[(k + 0) * ED + j];
                a1 += (double)hbuf[k + 1] * (double)W2[(k + 1) * ED + j];
                a2 += (double)hbuf[k + 2] * (double)W2[(k + 2) * ED + j];
                a3 += (double)hbuf[k + 3] * (double)W2[(k + 3) * ED + j];
            }
            double mv = (double)b2[j] + ((a0 + a1) + (a2 + a3));
            int mi = j;
            #pragma unroll
            for (int m = 1; m < 64; m <<= 1) {
                const double ov = __shfl_xor(mv, m);
                const int    oi = __shfl_xor(mi, m);
                if (ov > mv || (ov == mv && oi < mi)) { mv = ov; mi = oi; }
            }
            if ((j & 63) == 0) { rvd[j >> 6] = mv; ri[j >> 6] = mi; }
            __syncthreads();
            int gi;
            if (rvd[1] > rvd[0] || (rvd[1] == rvd[0] && ri[1] < ri[0])) gi = ri[1];
            else gi = ri[0];
            if (j == 0) ftab[(size_t)t * ED + i] = (unsigned char)gi;
            __syncthreads();
        }
        __syncthreads();
    }
}

// ---------------------------------------------------------------------------
// Phase C: per-chunk hypothesis walk + compact final map.
// ---------------------------------------------------------------------------
__global__ void __launch_bounds__(128) walk_kernel(
    const unsigned char* __restrict__ ftab, unsigned char* __restrict__ walk,
    unsigned char* __restrict__ finmap)
{
    const int c   = blockIdx.x;
    const int tid = threadIdx.x;
    __shared__ unsigned char F[512 * 128];   // 64 KB

    const uint4* src = reinterpret_cast<const uint4*>(ftab + (size_t)c * 512 * 128);
    uint4* dst = reinterpret_cast<uint4*>(F);
    for (int e = tid; e < 512 * 128 / 16; e += 128) {
        uint4 v = src[e];
        v.x &= 0x7f7f7f7fu; v.y &= 0x7f7f7f7fu; v.z &= 0x7f7f7f7fu; v.w &= 0x7f7f7f7fu;
        dst[e] = v;
    }
    __syncthreads();

    int s = tid;
    unsigned char* wbase = walk + (size_t)c * 512 * 128;
    for (int tt = 0; tt < 512; ++tt) {
        s = F[tt * 128 + s];
        wbase[tt * 128 + tid] = (unsigned char)s;
    }
    finmap[c * 128 + tid] = (unsigned char)s;
}

__global__ void compose_kernel(const unsigned char* __restrict__ finmap,
                               const int* __restrict__ eidx,
                               unsigned char* __restrict__ echain)
{
    if (blockIdx.x == 0 && threadIdx.x == 0) {
        int e = eidx[0];
        for (int c = 0; c < 128; ++c) {
            echain[c] = (unsigned char)e;
            e = finmap[c * 128 + e];
        }
    }
}

// ---------------------------------------------------------------------------
// Phase D (MFMA): logp/emb/idx for all t. Block = 512 thr, 128 t.
// ---------------------------------------------------------------------------
__global__ void __launch_bounds__(512, 1) outm_kernel(
    const float* pre, const float* __restrict__ E2,
    const unsigned short* __restrict__ W2Th, const unsigned short* __restrict__ W2Tl,
    const float* __restrict__ b2,
    const unsigned char* __restrict__ walk, const unsigned char* __restrict__ echain,
    const float* __restrict__ emb,
    float* out_logp, float* __restrict__ out_emb, float* __restrict__ out_idx)
{
    const int tid = threadIdx.x;
    const int w   = tid >> 6;
    const int l   = tid & 63;
    const int ibase = (w >> 1) * 32;
    const int jhalf = w & 1;
    const int j0    = jhalf * 64;
    const int lc = l & 15, lg = l >> 4;
    const int t0 = blockIdx.x << 7;
    const int ec = echain[t0 >> 9];       // 128 | 512 -> constant per block

    __shared__ float smM[2][128];
    __shared__ float smS[2][128];
    __shared__ float smLSE[128];

    // B fragments
    bf16x8 Bh[4][4], Bl[4][4];
    #pragma unroll
    for (int jt = 0; jt < 4; ++jt)
        #pragma unroll
        for (int kk = 0; kk < 4; ++kk) {
            const int row = j0 + jt * 16 + lc;
            const int kof = kk * 32 + (lg << 3);
            Bh[jt][kk] = load_frag(W2Th + row * TMPD + kof);
            Bl[jt][kk] = load_frag(W2Tl + row * TMPD + kof);
        }
    float b2v[4];
    #pragma unroll
    for (int jt = 0; jt < 4; ++jt) b2v[jt] = b2[j0 + jt * 16 + lc];

    // previous state for this lane's two A-rows
    int si[2];
    #pragma unroll
    for (int it = 0; it < 2; ++it) {
        const int t = t0 + ibase + it * 16 + lc;
        si[it] = ((t & 511) == 0) ? ec : (int)walk[(size_t)(t - 1) * 128 + ec];
    }

    // ---- MFMA: logits = lrelu(PRE + E2[si]) @ W2 ----
    f32x4 acc[2][4];
    #pragma unroll
    for (int it = 0; it < 2; ++it)
        #pragma unroll
        for (int jt = 0; jt < 4; ++jt)
            acc[it][jt] = (f32x4){0.f, 0.f, 0.f, 0.f};

    #pragma unroll
    for (int kk = 0; kk < 4; ++kk) {
        const int kof = kk * 32 + (lg << 3);
        bf16x8 Ah[2], Al[2];
        #pragma unroll
        for (int it = 0; it < 2; ++it) {
            const float* pA = pre + (size_t)(t0 + ibase + it * 16 + lc) * TMPD + kof;
            const float* eA = E2 + (size_t)si[it] * TMPD + kof;
            const float4 p0 = *reinterpret_cast<const float4*>(pA);
            const float4 p1 = *reinterpret_cast<const float4*>(pA + 4);
            const float4 e0 = *reinterpret_cast<const float4*>(eA);
            const float4 e1 = *reinterpret_cast<const float4*>(eA + 4);
            split8(p0, p1, e0, e1, Ah[it], Al[it]);
        }
        #pragma unroll
        for (int it = 0; it < 2; ++it)
            #pragma unroll
            for (int jt = 0; jt < 4; ++jt) {
                acc[it][jt] = __builtin_amdgcn_mfma_f32_16x16x32_bf16(Al[it], Bh[jt][kk], acc[it][jt], 0, 0, 0);
                acc[it][jt] = __builtin_amdgcn_mfma_f32_16x16x32_bf16(Ah[it], Bl[jt][kk], acc[it][jt], 0, 0, 0);
                acc[it][jt] = __builtin_amdgcn_mfma_f32_16x16x32_bf16(Ah[it], Bh[jt][kk], acc[it][jt], 0, 0, 0);
            }
    }

    // ---- per-row max & sum over this wave's 64 j ----
    #pragma unroll
    for (int it = 0; it < 2; ++it) {
        #pragma unroll
        for (int r = 0; r < 4; ++r) {
            float v0 = acc[it][0][r] + b2v[0];
            float v1 = acc[it][1][r] + b2v[1];
            float v2 = acc[it][2][r] + b2v[2];
            float v3 = acc[it][3][r] + b2v[3];
            float mx = fmaxf(fmaxf(v0, v1), fmaxf(v2, v3));
            #pragma unroll
            for (int m = 1; m < 16; m <<= 1)
                mx = fmaxf(mx, __shfl_xor(mx, m));
            float s = expf(v0 - mx) + expf(v1 - mx) + expf(v2 - mx) + expf(v3 - mx);
            #pragma unroll
            for (int m = 1; m < 16; m <<= 1)
                s += __shfl_xor(s, m);
            if (lc == 0) {
                const int row = ibase + it * 16 + 4 * lg + r;
                smM[jhalf][row] = mx;
                smS[jhalf][row] = s;
            }
        }
    }
    __syncthreads();

    // ---- merge halves -> lse per row ----
    if (tid < 128) {
        const float m0 = smM[0][tid], m1 = smM[1][tid];
        const float s0 = smS[0][tid], s1 = smS[1][tid];
        const float m = fmaxf(m0, m1);
        smLSE[tid] = m + logf(s0 * expf(m0 - m) + s1 * expf(m1 - m));
    }
    __syncthreads();

    // ---- write logp ----
    #pragma unroll
    for (int it = 0; it < 2; ++it) {
        #pragma unroll
        for (int r = 0; r < 4; ++r) {
            const int row = ibase + it * 16 + 4 * lg + r;
            const float lse = smLSE[row];
            const int t = t0 + row;
            #pragma unroll
            for (int jt = 0; jt < 4; ++jt)
                out_logp[(size_t)t * TMPD + j0 + jt * 16 + lc] =
                    acc[it][jt][r] + b2v[jt] - lse;
        }
    }

    // ---- emb / idx ----
    if (tid < 128) {
        const int t  = t0 + tid;
        const int gi = walk[(size_t)t * 128 + ec];
        out_idx[t] = (float)gi;
        const float4* es = reinterpret_cast<const float4*>(emb + (size_t)gi * EMBD);
        float4*       ed = reinterpret_cast<float4*>(out_emb + (size_t)t * EMBD);
        #pragma unroll
        for (int q = 0; q < 4; ++q) ed[q] = es[q];
    }
}

// ---------------------------------------------------------------------------
// Fallback (ws too small): round-1 sequential kernel (known-good).
// ---------------------------------------------------------------------------
__global__ void __launch_bounds__(128, 1) seq_kernel(
    const float* pre_in, const int* __restrict__ eidx,
    const float* __restrict__ emb, const float* __restrict__ W1,
    const float* __restrict__ W2, const float* __restrict__ b2,
    float* out_logp, float* __restrict__ out_emb, float* __restrict__ out_idx)
{
    const int j = threadIdx.x;
    __shared__ float  E2s[ED * TMPD];
    __shared__ float  hbuf[TMPD];
    __shared__ double rvd[2];
    __shared__ int    ri[2];
    __shared__ float  rs[2];

    for (int i = 0; i < ED; ++i) {
        double a = 0.0;
        #pragma unroll
        for (int m = 0; m < EMBD; ++m)
            a += (double)emb[i * EMBD + m] * (double)W1[(HID + m) * TMPD + j];
        E2s[i * TMPD + j] = (float)a;
    }
    float w2c[TMPD];
    #pragma unroll 8
    for (int k = 0; k < TMPD; ++k) w2c[k] = W2[k * ED + j];
    const float bias2 = b2[j];
    int idx = eidx[0];
    __syncthreads();

    float pre_cur = pre_in[j];
    for (int t = 0; t < TT; ++t) {
        float pre_next = (t + 1 < TT) ? pre_in[(size_t)(t + 1) * TMPD + j] : 0.0f;
        float h = pre_cur + E2s[idx * TMPD + j];
        h = fmaxf(h, 0.01f * h);
        hbuf[j] = h;
        __syncthreads();
        double a0 = 0, a1 = 0, a2 = 0, a3 = 0;
        #pragma unroll
        for (int k = 0; k < TMPD; k += 4) {
            a0 += (double)hbuf[k + 0] * (double)w2c[k + 0];
            a1 += (double)hbuf[k + 1] * (double)w2c[k + 1];
            a2 += (double)hbuf[k + 2] * (double)w2c[k + 2];
            a3 += (double)hbuf[k + 3] * (double)w2c[k + 3];
        }
        const double logitd = (double)bias2 + ((a0 + a1) + (a2 + a3));
        const float  logit  = (float)logitd;
        double mv = logitd; int mi = j;
        #pragma unroll
        for (int m = 1; m < 64; m <<= 1) {
            double ov = __shfl_xor(mv, m);
            int    oi = __shfl_xor(mi, m);
            if (ov > mv || (ov == mv && oi < mi)) { mv = ov; mi = oi; }
        }
        if ((j & 63) == 0) { rvd[j >> 6] = mv; ri[j >> 6] = mi; }
        __syncthreads();
        int gi; double gmd;
        if (rvd[1] > rvd[0] || (rvd[1] == rvd[0] && ri[1] < ri[0])) { gmd = rvd[1]; gi = ri[1]; }
        else { gmd = rvd[0]; gi = ri[0]; }
        const float gm = (float)gmd;
        float e = expf(logit - gm);
        float s = e;
        #pragma unroll
        for (int m = 1; m < 64; m <<= 1) s += __shfl_xor(s, m);
        if ((j & 63) == 0) rs[j >> 6] = s;
        __syncthreads();
        const float lse = gm + logf(rs[0] + rs[1]);
        out_logp[(size_t)t * TMPD + j] = logit - lse;
        if (j < EMBD) out_emb[(size_t)t * EMBD + j] = emb[gi * EMBD + j];
        if (j == 0)   out_idx[t] = (float)gi;
        idx = gi;
        pre_cur = pre_next;
        __syncthreads();
    }
}

// ---------------------------------------------------------------------------
extern "C" void kernel_launch(void* const* d_in, const int* in_sizes, int n_in,
                              void* d_out, int out_size, void* d_ws, size_t ws_size,
                              hipStream_t stream)
{
    const float* x    = (const float*)d_in[0];
    const int*   eidx = (const int*)  d_in[1];
    const float* emb  = (const float*)d_in[2];
    const float* W1   = (const float*)d_in[3];
    const float* b1   = (const float*)d_in[4];
    const float* W2   = (const float*)d_in[5];
    const float* b2   = (const float*)d_in[6];

    float* out0 = (float*)d_out;                 // logp  (T*128) = 32 MB
    float* out1 = out0 + (size_t)TT * TMPD;      // emb   (T*16)
    float* out2 = out1 + (size_t)TT * EMBD;      // index (T)

    // ---- workspace layout ----
    const size_t OFF_E2    = 0;                          // 64 KB
    const size_t OFF_E2T4  = OFF_E2    + 64 * 1024;      // 64 KB
    const size_t OFF_W2TH  = OFF_E2T4  + 64 * 1024;      // 32 KB
    const size_t OFF_W2TL  = OFF_W2TH  + 32 * 1024;      // 32 KB
    const size_t OFF_W2TF  = OFF_W2TL  + 32 * 1024;      // 64 KB
    const size_t OFF_DP    = OFF_W2TF  + 64 * 1024;      // 4 KB
    const size_t OFF_META  = OFF_DP    + 4 * 1024;       // 4 KB
    const size_t OFF_CCNT  = OFF_META  + 4 * 1024;       // 64 KB
    const size_t OFF_ECHN  = OFF_CCNT  + 64 * 1024;      // 4 KB
    const size_t OFF_FIN   = OFF_ECHN  + 4 * 1024;       // 16 KB
    const size_t OFF_TLIST = OFF_FIN   + 16 * 1024;      // 256 KB
    const size_t OFF_CLIST = OFF_TLIST + 256 * 1024;     // 2 MB
    const size_t OFF_FTAB  = OFF_CLIST + 2048 * 1024;    // 8 MB
    const size_t OFF_WALK  = OFF_FTAB  + (size_t)TT * ED;        // 8 MB
    const size_t OFF_WORK  = OFF_WALK  + (size_t)TT * ED;        // 4 MB
    const size_t AUXN      = OFF_WORK  + (size_t)CAPW * 4;
    const size_t PRE_B     = (size_t)TT * TMPD * sizeof(float);  // 32 MB

    unsigned char* wsb = (unsigned char*)d_ws;
    float*          E2    = (float*)(wsb + OFF_E2);
    float*          E2T4  = (float*)(wsb + OFF_E2T4);
    unsigned short* W2Th  = (unsigned short*)(wsb + OFF_W2TH);
    unsigned short* W2Tl  = (unsigned short*)(wsb + OFF_W2TL);
    float*          W2Tf  = (float*)(wsb + OFF_W2TF);
    float*          Dp    = (float*)(wsb + OFF_DP);
    unsigned int*   meta  = (unsigned int*)(wsb + OFF_META);
    unsigned char*  ccnt  = wsb + OFF_CCNT;
    unsigned char*  echn  = wsb + OFF_ECHN;
    unsigned char*  fin   = wsb + OFF_FIN;
    unsigned int*   tlist = (unsigned int*)(wsb + OFF_TLIST);
    unsigned char*  clist = wsb + OFF_CLIST;
    unsigned char*  ftab  = wsb + OFF_FTAB;
    unsigned char*  walk  = wsb + OFF_WALK;
    unsigned int*   work  = (unsigned int*)(wsb + OFF_WORK);

    if (ws_size >= AUXN) {
        float* pre = (ws_size >= AUXN + PRE_B) ? (float*)(wsb + AUXN) : out0;

        pre_kernel    <<<TT / TPRE, 256, 0, stream>>>(x, W1, b1, pre);
        w2split_kernel<<<64,       256, 0, stream>>>(W2, W2Th, W2Tl, W2Tf);
        e2z_kernel    <<<128,      128, 0, stream>>>(emb, W1, E2, E2T4, meta);
        dp_kernel     <<<128,      128, 0, stream>>>(E2, W2Tf, Dp);
        l0_kernel     <<<TT / 128, 512, 0, stream>>>(pre, W2Th, W2Tl, b2, Dp,
                                                     ftab, clist, ccnt, tlist, meta);
        tier2_kernel  <<<4096,     128, 0, stream>>>(pre, E2T4, W2Tf, b2, meta,
                                                     tlist, ccnt, clist, ftab);
        compact_kernel<<<TT * ED / 4 / 256, 256, 0, stream>>>(ftab, meta, work);
        repair3_kernel<<<8192,      64, 0, stream>>>(pre, E2, W2Tf, b2, clist,
                                                     ccnt, meta, work, ftab);
        repair_kernel <<<TT / TPB, 128, 0, stream>>>(pre, E2, W2, b2, meta, ftab);
        walk_kernel   <<<TT / 512, 128, 0, stream>>>(ftab, walk, fin);
        compose_kernel<<<1,         64, 0, stream>>>(fin, eidx, echn);
        outm_kernel   <<<TT / 128, 512, 0, stream>>>(pre, E2, W2Th, W2Tl, b2,
                                                     walk, echn, emb,
                                                     out0, out1, out2);
    } else {
        float* pre2 = (ws_size >= PRE_B) ? (float*)d_ws : out0;
        preold_kernel<<<TT / 16, 128, 0, stream>>>(x, W1, b1, pre2);
        seq_kernel<<<1, 128, 0, stream>>>(pre2, eidx, emb, W1, W2, b2,
                                          out0, out1, out2);
    }
}